// Round 1
// 267.831 us; speedup vs baseline: 1.0037x; 1.0037x over previous
//
#include <hip/hip_runtime.h>

// BondWeight: out[b, src+1, dst+1] = w; out[b, dst+1, src+1] = w (two passes,
// last-write-wins within the 1024-write per-batch sequence, numpy semantics).
// B=1024, E=512, T=8, N=256. Output 256 MB f32 -> pure HBM-write-bound.
//
// Strategy: merge scatter into the streaming write so every output line is
// written exactly once. Per batch block, a u16 LDS table over a 64-row chunk
// holds packed=(seq+1)<<3|type per cell; CAS-based 16-bit max implements
// last-write-wins. Stream the chunk as coalesced float4 stores.
//
// R4 change vs R3 (~101 us kernel vs ~43 us store floor; harness dur also
// contains a fixed ~167 us poison fill we cannot touch):
//  THEORY: all 1024 blocks run the identical barrier-timed schedule over
//  256KB regions at stride 256KB -> at any instant every block writes the
//  same offset-within-region (identical low 18 addr bits) -> HBM channel
//  camping; fill kernel sweeps uniformly and gets 6.4 TB/s, we get ~2.7.
//  FIX: per-block phase rotation of the write sweep:
//    - chunk visit order rotated by (b & 3)
//    - intra-chunk iteration start rotated by ((b >> 2) & 15)
//  -> 64 distinct instantaneous write phases across the grid. Coalescing,
//  chunk independence, CAS semantics unchanged.

#define NB_E 512
#define NB_N 256
#define CH_ROWS 64
#define CH_WORDS (CH_ROWS * NB_N / 2)   // 8192 u32 = 32 KB LDS

typedef float v4f __attribute__((ext_vector_type(4)));

__device__ __forceinline__ void lds_max_u16(unsigned int* tab, int cell, unsigned int v16)
{
    unsigned int* w = tab + (cell >> 1);
    const int sh = (cell & 1) * 16;
    unsigned int old = *w;
    while (true) {
        const unsigned int cur = (old >> sh) & 0xFFFFu;
        if (cur >= v16) break;                       // current winner is later
        const unsigned int nw = (old & ~(0xFFFFu << sh)) | (v16 << sh);
        const unsigned int seen = atomicCAS(w, old, nw);
        if (seen == old) break;
        old = seen;                                  // contended: retry
    }
}

__global__ __launch_bounds__(256) void BondWeight_41738492182540_kernel(
    const float* __restrict__ weights,
    const int*   __restrict__ bsrc,
    const int*   __restrict__ bdst,
    const int*   __restrict__ btyp,
    float*       __restrict__ out)
{
    __shared__ unsigned int seqtab[CH_WORDS];
    __shared__ float s_wt[8];

    const int b = blockIdx.x;
    const int t = threadIdx.x;

    if (t < 8) s_wt[t] = weights[t];

    // My two edges -> four writes. seq order: pass1 (src,dst) e=0..511 then
    // pass2 (dst,src) e=0..511. packed = (seq+1)<<3 | type; max == last wins.
    const int ebase = b * NB_E;
    int row[4], col[4];
    unsigned int pk[4];
    #pragma unroll
    for (int i = 0; i < 2; ++i) {
        const int e  = t + 256 * i;
        const int s1 = bsrc[ebase + e] + 1;          // [1, 255]
        const int d1 = bdst[ebase + e] + 1;
        const unsigned int ty = (unsigned int)btyp[ebase + e] & 7u;
        row[2*i]   = s1; col[2*i]   = d1; pk[2*i]   = ((unsigned int)(e + 1) << 3) | ty;
        row[2*i+1] = d1; col[2*i+1] = s1; pk[2*i+1] = ((unsigned int)(NB_E + e + 1) << 3) | ty;
    }

    // --- zero the table ONCE: 8192 u32, uint4 x 8 per thread ---
    {
        uint4* tab4 = (uint4*)seqtab;
        #pragma unroll
        for (int k = 0; k < CH_WORDS / 4 / 256; ++k)
            tab4[t + 256 * k] = make_uint4(0u, 0u, 0u, 0u);
    }
    __syncthreads();

    float4* __restrict__ out4 = ((float4*)out) + (size_t)b * (NB_N * NB_N / 4);
    uint2*  __restrict__ tab2 = (uint2*)seqtab;

    const int crot = b & 3;         // chunk-order rotation (4 phases)
    const int krot = (b >> 2) & 15; // intra-chunk start rotation (16 phases)

    for (int cc = 0; cc < 4; ++cc) {
        const int r0 = ((cc + crot) & 3) * CH_ROWS;

        // --- scatter my writes that land in this row chunk (table is clean) ---
        #pragma unroll
        for (int i = 0; i < 4; ++i) {
            const int r = row[i] - r0;
            if (0 <= r && r < CH_ROWS)
                lds_max_u16(seqtab, r * NB_N + col[i], pk[i]);
        }
        __syncthreads();

        // --- stream chunk: 4096 float4, 16/thread, coalesced; re-zero as we go.
        // Iteration start rotated per block to decorrelate HBM write phases. ---
        #pragma unroll
        for (int j = 0; j < (CH_ROWS * NB_N / 4) / 256; ++j) {
            const int i4 = t + 256 * ((j + krot) & 15);
            const uint2 ab = tab2[i4];               // ds_read_b64
            tab2[i4] = make_uint2(0u, 0u);           // clean for next chunk's CAS
            v4f v;
            unsigned int p;
            p = ab.x & 0xFFFFu; v.x = p ? s_wt[p & 7u] : 0.0f;
            p = ab.x >> 16;     v.y = p ? s_wt[p & 7u] : 0.0f;
            p = ab.y & 0xFFFFu; v.z = p ? s_wt[p & 7u] : 0.0f;
            p = ab.y >> 16;     v.w = p ? s_wt[p & 7u] : 0.0f;
            *(v4f*)&out4[r0 * (NB_N / 4) + i4] = v;  // plain store: completes in L2
        }
        __syncthreads();   // stream+rezero done before next chunk's CAS
    }
}

extern "C" void kernel_launch(void* const* d_in, const int* in_sizes, int n_in,
                              void* d_out, int out_size, void* d_ws, size_t ws_size,
                              hipStream_t stream) {
    const float* weights = (const float*)d_in[0];   // [T=8]
    const int*   bsrc    = (const int*)d_in[1];     // [B, E]
    const int*   bdst    = (const int*)d_in[2];     // [B, E]
    const int*   btyp    = (const int*)d_in[3];     // [B, E]
    float*       out     = (float*)d_out;           // [B, N, N] f32

    const int nb = in_sizes[1] / NB_E;              // B = 1024

    BondWeight_41738492182540_kernel<<<nb, 256, 0, stream>>>(
        weights, bsrc, bdst, btyp, out);
}